// Round 6
// baseline (386.624 us; speedup 1.0000x reference)
//
#include <hip/hip_runtime.h>
#include <math.h>

#define D_ 8
#define H_ 64
#define IN_ 17
#define SLOPE_ 0.2f
#define B_ 128
#define T_ 514
#define W_ 512
#define N_ (B_*W_)            // 65536
#define RES_SZ (N_*D_)        // 524288
#define LOG_OFF RES_SZ        // 524288
#define HJ_OFF (RES_SZ + B_)  // 524416

#define P1S 84   // packed row: [W1T row (64) | W0 row (17) | b0 (1) | pad 2]
#define P2S 68   // packed row: [W2 row (64) | b2 | Wo | pad 2]
#define P2_OFF (D_*H_*P1S)

// Packs weights into row-contiguous records and zero-inits the logdet region.
__global__ void setup_kernel(const float* __restrict__ W0, const float* __restrict__ b0,
                             const float* __restrict__ W1, const float* __restrict__ W2,
                             const float* __restrict__ b2, const float* __restrict__ Wo,
                             float* __restrict__ ws, float* __restrict__ out) {
    int d = blockIdx.x;
    float* p1 = ws + d * H_ * P1S;
    float* p2 = ws + P2_OFF + d * H_ * P2S;
    for (int idx = threadIdx.x; idx < H_ * H_; idx += blockDim.x) {
        int r = idx >> 6, c = idx & 63;
        p1[r * P1S + c] = W1[(d * H_ + c) * H_ + r];   // W1T[r][c] = W1[d][c][r]
        p2[r * P2S + c] = W2[(d * H_ + r) * H_ + c];   // W2 row r
    }
    for (int r = threadIdx.x; r < H_; r += blockDim.x) {
        for (int i = 0; i < IN_; ++i)
            p1[r * P1S + 64 + i] = W0[(d * H_ + r) * IN_ + i];
        p1[r * P1S + 81] = b0[d * H_ + r];
        p2[r * P2S + 64] = b2[d * H_ + r];
        p2[r * P2S + 65] = Wo[d * H_ + r];
    }
    if (d == 0 && threadIdx.x < B_) out[LOG_OFF + threadIdx.x] = 0.0f;
}

// Lane-pair split: sample handled by (lane, lane^32). Each thread owns half
// the 64-wide hidden state (h1[32], g2[32]) -> peak regs ~105 -> 4 waves/SIMD,
// enough TLP to hide LDS row-load latency that R1-R5 (1.7-3.3 waves/SIMD)
// could not. Hidden-dim dots = partial dot + one __shfl_xor(.,32).
__global__ __launch_bounds__(256, 4) void mlp_kernel(
    const float* __restrict__ x,
    const float* __restrict__ b1g,
    const float* __restrict__ bo,
    const float* __restrict__ ws,
    float* __restrict__ out)
{
    __shared__ float sP1[H_ * P1S];   // 5376 floats
    __shared__ float sP2[H_ * P2S];   // 4352 floats
    __shared__ float sb1[H_];
    __shared__ float red[4];

    const int bid = blockIdx.x;
    const int d   = bid >> 9;            // 512 blocks per d
    const int rem = bid & 511;
    const int b   = rem >> 2;
    const int qt  = rem & 3;             // quarter of the 512 windows

    const int tid  = threadIdx.x;
    const int wave = tid >> 6;
    const int lane = tid & 63;
    const int hh   = lane >> 5;          // half id: 0 -> units/k 0..31, 1 -> 32..63
    const int base = hh << 5;
    const int sl   = (lane & 31) + (wave << 5);   // sample in block 0..127
    const int w    = (qt << 7) | sl;
    const int n    = b * W_ + w;

    // ---- stage packed weights into LDS (one-time per block)
    {
        const float4* g1 = (const float4*)(ws + d * H_ * P1S);
        const float4* g2 = (const float4*)(ws + P2_OFF + d * H_ * P2S);
        float4* l1 = (float4*)sP1;
        float4* l2 = (float4*)sP2;
        for (int i = tid; i < H_ * P1S / 4; i += 256) l1[i] = g1[i];
        for (int i = tid; i < H_ * P2S / 4; i += 256) l2[i] = g2[i];
        if (tid < H_) sb1[tid] = b1g[d * H_ + tid];
    }

    // ---- gather window input while staging lands (pair threads duplicate this)
    float inp[IN_];
    {
        const float* xp = x + (b * T_ + w) * D_;
        const float4* xp4 = (const float4*)xp;
        float4 q0 = xp4[0], q1 = xp4[1], q2 = xp4[2], q3 = xp4[3];
        inp[0]=q0.x;  inp[1]=q0.y;  inp[2]=q0.z;  inp[3]=q0.w;
        inp[4]=q1.x;  inp[5]=q1.y;  inp[6]=q1.z;  inp[7]=q1.w;
        inp[8]=q2.x;  inp[9]=q2.y;  inp[10]=q2.z; inp[11]=q2.w;
        inp[12]=q3.x; inp[13]=q3.y; inp[14]=q3.z; inp[15]=q3.w;
        inp[16] = xp[16 + d];
    }
    __syncthreads();

    // ---- Phase A: each thread computes a0 for 32 units (own half), outer-product
    //      accumulates BOTH halves' a0 into its own g-half of h1.
    float h1[32];
#pragma unroll
    for (int g = 0; g < 32; ++g) h1[g] = sb1[base + g];

    unsigned int m0own = 0u;

#pragma unroll 2
    for (int h = 0; h < 32; ++h) {
        const int unit = base + h;
        const float4* wr = (const float4*)(sP1 + unit * P1S + 64);
        float4 wa = wr[0], wb = wr[1], wc = wr[2], wd = wr[3], wt = wr[4]; // wt.x=W0[16], wt.y=b0
        float t0 = wt.y, t1 = 0.f, t2 = 0.f, t3 = 0.f;
        t0 = fmaf(inp[0],  wa.x, t0); t1 = fmaf(inp[1],  wa.y, t1);
        t2 = fmaf(inp[2],  wa.z, t2); t3 = fmaf(inp[3],  wa.w, t3);
        t0 = fmaf(inp[4],  wb.x, t0); t1 = fmaf(inp[5],  wb.y, t1);
        t2 = fmaf(inp[6],  wb.z, t2); t3 = fmaf(inp[7],  wb.w, t3);
        t0 = fmaf(inp[8],  wc.x, t0); t1 = fmaf(inp[9],  wc.y, t1);
        t2 = fmaf(inp[10], wc.z, t2); t3 = fmaf(inp[11], wc.w, t3);
        t0 = fmaf(inp[12], wd.x, t0); t1 = fmaf(inp[13], wd.y, t1);
        t2 = fmaf(inp[14], wd.z, t2); t3 = fmaf(inp[15], wd.w, t3);
        t0 = fmaf(inp[16], wt.x, t0);
        float hv = (t0 + t2) + (t1 + t3);
        bool  p  = hv > 0.0f;
        float a  = p ? hv : hv * SLOPE_;
        m0own |= ((unsigned int)p) << h;

        float ap    = __shfl_xor(a, 32, 64);
        float aLow  = hh ? ap : a;     // a0 of unit h
        float aHigh = hh ? a  : ap;    // a0 of unit 32+h

        const float4* rA = (const float4*)(sP1 + h        * P1S + base);
        const float4* rB = (const float4*)(sP1 + (32 + h) * P1S + base);
#pragma unroll
        for (int q = 0; q < 8; ++q) {
            float4 v = rA[q];
            h1[4*q+0] = fmaf(aLow, v.x, h1[4*q+0]);
            h1[4*q+1] = fmaf(aLow, v.y, h1[4*q+1]);
            h1[4*q+2] = fmaf(aLow, v.z, h1[4*q+2]);
            h1[4*q+3] = fmaf(aLow, v.w, h1[4*q+3]);
        }
#pragma unroll
        for (int q = 0; q < 8; ++q) {
            float4 v = rB[q];
            h1[4*q+0] = fmaf(aHigh, v.x, h1[4*q+0]);
            h1[4*q+1] = fmaf(aHigh, v.y, h1[4*q+1]);
            h1[4*q+2] = fmaf(aHigh, v.z, h1[4*q+2]);
            h1[4*q+3] = fmaf(aHigh, v.w, h1[4*q+3]);
        }
    }
    // inp dead.

    // exchange m0 halves so both threads hold the full 64-bit mask
    unsigned int m0p = (unsigned int)__shfl_xor((int)m0own, 32, 64);
    unsigned long long m0full = hh ? ((((unsigned long long)m0own) << 32) | m0p)
                                   : ((((unsigned long long)m0p)  << 32) | m0own);

    // ---- Phase B: leaky in place + m1 mask (own half)
    unsigned int m1own = 0u;
#pragma unroll
    for (int g = 0; g < 32; ++g) {
        float v = h1[g];
        bool  p = v > 0.0f;
        m1own |= ((unsigned int)p) << g;
        h1[g] = p ? v : v * SLOPE_;
    }

    // ---- Phase C: layer2 dot (partial + shfl) + out-dot + backward-through-W2 outer
    float g2[32];
#pragma unroll
    for (int k = 0; k < 32; ++k) g2[k] = 0.0f;
    float outv = bo[d];

#pragma unroll 2
    for (int g = 0; g < H_; ++g) {
        const float4* row = (const float4*)(sP2 + g * P2S + base);
        float4 r0 = row[0], r1 = row[1], r2 = row[2], r3 = row[3];
        float4 r4 = row[4], r5 = row[5], r6 = row[6], r7 = row[7];
        float4 e  = *((const float4*)(sP2 + g * P2S + 64));   // e.x=b2, e.y=Wo
        float t0 = 0.f, t1 = 0.f, t2 = 0.f, t3 = 0.f;
        t0 = fmaf(h1[0],  r0.x, t0); t1 = fmaf(h1[1],  r0.y, t1);
        t2 = fmaf(h1[2],  r0.z, t2); t3 = fmaf(h1[3],  r0.w, t3);
        t0 = fmaf(h1[4],  r1.x, t0); t1 = fmaf(h1[5],  r1.y, t1);
        t2 = fmaf(h1[6],  r1.z, t2); t3 = fmaf(h1[7],  r1.w, t3);
        t0 = fmaf(h1[8],  r2.x, t0); t1 = fmaf(h1[9],  r2.y, t1);
        t2 = fmaf(h1[10], r2.z, t2); t3 = fmaf(h1[11], r2.w, t3);
        t0 = fmaf(h1[12], r3.x, t0); t1 = fmaf(h1[13], r3.y, t1);
        t2 = fmaf(h1[14], r3.z, t2); t3 = fmaf(h1[15], r3.w, t3);
        t0 = fmaf(h1[16], r4.x, t0); t1 = fmaf(h1[17], r4.y, t1);
        t2 = fmaf(h1[18], r4.z, t2); t3 = fmaf(h1[19], r4.w, t3);
        t0 = fmaf(h1[20], r5.x, t0); t1 = fmaf(h1[21], r5.y, t1);
        t2 = fmaf(h1[22], r5.z, t2); t3 = fmaf(h1[23], r5.w, t3);
        t0 = fmaf(h1[24], r6.x, t0); t1 = fmaf(h1[25], r6.y, t1);
        t2 = fmaf(h1[26], r6.z, t2); t3 = fmaf(h1[27], r6.w, t3);
        t0 = fmaf(h1[28], r7.x, t0); t1 = fmaf(h1[29], r7.y, t1);
        t2 = fmaf(h1[30], r7.z, t2); t3 = fmaf(h1[31], r7.w, t3);
        float pa  = (t0 + t2) + (t1 + t3);
        float tot = pa + __shfl_xor(pa, 32, 64);
        float hv  = tot + e.x;
        bool  p   = hv > 0.0f;
        outv = fmaf(e.y, p ? hv : hv * SLOPE_, outv);
        float gb = e.y * (p ? 1.0f : SLOPE_);
        g2[0]  = fmaf(gb, r0.x, g2[0]);  g2[1]  = fmaf(gb, r0.y, g2[1]);
        g2[2]  = fmaf(gb, r0.z, g2[2]);  g2[3]  = fmaf(gb, r0.w, g2[3]);
        g2[4]  = fmaf(gb, r1.x, g2[4]);  g2[5]  = fmaf(gb, r1.y, g2[5]);
        g2[6]  = fmaf(gb, r1.z, g2[6]);  g2[7]  = fmaf(gb, r1.w, g2[7]);
        g2[8]  = fmaf(gb, r2.x, g2[8]);  g2[9]  = fmaf(gb, r2.y, g2[9]);
        g2[10] = fmaf(gb, r2.z, g2[10]); g2[11] = fmaf(gb, r2.w, g2[11]);
        g2[12] = fmaf(gb, r3.x, g2[12]); g2[13] = fmaf(gb, r3.y, g2[13]);
        g2[14] = fmaf(gb, r3.z, g2[14]); g2[15] = fmaf(gb, r3.w, g2[15]);
        g2[16] = fmaf(gb, r4.x, g2[16]); g2[17] = fmaf(gb, r4.y, g2[17]);
        g2[18] = fmaf(gb, r4.z, g2[18]); g2[19] = fmaf(gb, r4.w, g2[19]);
        g2[20] = fmaf(gb, r5.x, g2[20]); g2[21] = fmaf(gb, r5.y, g2[21]);
        g2[22] = fmaf(gb, r5.z, g2[22]); g2[23] = fmaf(gb, r5.w, g2[23]);
        g2[24] = fmaf(gb, r6.x, g2[24]); g2[25] = fmaf(gb, r6.y, g2[25]);
        g2[26] = fmaf(gb, r6.z, g2[26]); g2[27] = fmaf(gb, r6.w, g2[27]);
        g2[28] = fmaf(gb, r7.x, g2[28]); g2[29] = fmaf(gb, r7.y, g2[29]);
        g2[30] = fmaf(gb, r7.z, g2[30]); g2[31] = fmaf(gb, r7.w, g2[31]);
    }

    if (hh == 0) out[n * D_ + d] = outv;   // residuals[b,w,d]

    // ---- Phase D: apply m1 (own half)
#pragma unroll
    for (int k = 0; k < 32; ++k)
        g2[k] *= (((m1own >> k) & 1u) ? 1.0f : SLOPE_);

    // ---- Phase E: backward through W1 (partial dot + shfl) + jac outer (split i-range)
    float jac[9];
#pragma unroll
    for (int i = 0; i < 9; ++i) jac[i] = 0.0f;

#pragma unroll 2
    for (int j = 0; j < H_; ++j) {
        const float4* row = (const float4*)(sP1 + j * P1S + base);
        float t0 = 0.f, t1 = 0.f, t2 = 0.f, t3 = 0.f;
#pragma unroll
        for (int q = 0; q < 8; ++q) {
            float4 v = row[q];
            t0 = fmaf(g2[4*q+0], v.x, t0);
            t1 = fmaf(g2[4*q+1], v.y, t1);
            t2 = fmaf(g2[4*q+2], v.z, t2);
            t3 = fmaf(g2[4*q+3], v.w, t3);
        }
        float pa  = (t0 + t2) + (t1 + t3);
        float tot = pa + __shfl_xor(pa, 32, 64);
        float g3  = tot * (((m0full >> j) & 1ull) ? 1.0f : SLOPE_);
        const float4* wr = (const float4*)(sP1 + j * P1S + 64 + 8 * hh);
        float4 va = wr[0], vb = wr[1];
        float e16 = sP1[j * P1S + 80];
        jac[0] = fmaf(g3, va.x, jac[0]); jac[1] = fmaf(g3, va.y, jac[1]);
        jac[2] = fmaf(g3, va.z, jac[2]); jac[3] = fmaf(g3, va.w, jac[3]);
        jac[4] = fmaf(g3, vb.x, jac[4]); jac[5] = fmaf(g3, vb.y, jac[5]);
        jac[6] = fmaf(g3, vb.z, jac[6]); jac[7] = fmaf(g3, vb.w, jac[7]);
        jac[8] = fmaf(g3, e16,  jac[8]);   // only meaningful for hh=1 (i=16)
    }

    // hist_jac[d][n][0..15]: low thread writes i 0..7, high writes i 8..15
    {
        float4* hj = (float4*)(out + HJ_OFF + ((size_t)(d * N_ + n)) * 16 + 8 * hh);
        hj[0] = make_float4(jac[0], jac[1], jac[2], jac[3]);
        hj[1] = make_float4(jac[4], jac[5], jac[6], jac[7]);
    }

    // logdet: only the high thread of each pair holds jac[16]
    float ld = hh ? logf(fabsf(jac[8])) : 0.0f;
#pragma unroll
    for (int off = 32; off > 0; off >>= 1)
        ld += __shfl_down(ld, off, 64);

    if ((lane & 63) == 0) red[wave] = ld;
    __syncthreads();
    if (tid == 0)
        atomicAdd(out + LOG_OFF + b, (red[0] + red[1]) + (red[2] + red[3]));
}

extern "C" void kernel_launch(void* const* d_in, const int* in_sizes, int n_in,
                              void* d_out, int out_size, void* d_ws, size_t ws_size,
                              hipStream_t stream) {
    const float* x  = (const float*)d_in[0];
    const float* W0 = (const float*)d_in[1];
    const float* b0 = (const float*)d_in[2];
    const float* W1 = (const float*)d_in[3];
    const float* b1 = (const float*)d_in[4];
    const float* W2 = (const float*)d_in[5];
    const float* b2 = (const float*)d_in[6];
    const float* Wo = (const float*)d_in[7];
    const float* bo = (const float*)d_in[8];
    float* out = (float*)d_out;
    float* ws  = (float*)d_ws;   // packs: (8*64*84 + 8*64*68)*4 = 311 KiB

    hipLaunchKernelGGL(setup_kernel, dim3(D_), dim3(256), 0, stream,
                       W0, b0, W1, W2, b2, Wo, ws, out);
    // 8 d * 128 b * 4 quarters = 4096 blocks; 128 samples/block (lane-pair split)
    hipLaunchKernelGGL(mlp_kernel, dim3(D_ * B_ * 4), dim3(256), 0, stream,
                       x, b1, bo, ws, out);
}

// Round 7
// 332.984 us; speedup vs baseline: 1.1611x; 1.1611x over previous
//
#include <hip/hip_runtime.h>
#include <math.h>

#define D_ 8
#define H_ 64
#define IN_ 17
#define SLOPE_ 0.2f
#define B_ 128
#define T_ 514
#define W_ 512
#define N_ (B_*W_)            // 65536
#define RES_SZ (N_*D_)        // 524288
#define LOG_OFF RES_SZ        // 524288
#define HJ_OFF (RES_SZ + B_)  // 524416

// ws layout: [0, 8*64*64) floats = W1T fp32 (forward).
// Then a ushort region with bf16 hi/lo planes for the backward GEMMs:
//   B1 = W2 [64x64], B2 = W1 [64x64], B3 = W0 padded [64x32] (cols 17..31 = 0)
#define WS_BF_OFF (D_*H_*H_)          // float offset where ushort region starts
#define UO_W2H 0
#define UO_W2L (UO_W2H + D_*H_*H_)
#define UO_W1H (UO_W2L + D_*H_*H_)
#define UO_W1L (UO_W1H + D_*H_*H_)
#define UO_W0H (UO_W1L + D_*H_*H_)
#define UO_W0L (UO_W0H + D_*H_*32)

typedef __attribute__((ext_vector_type(8))) short short8;
typedef __attribute__((ext_vector_type(4))) float float4v;

__device__ __forceinline__ unsigned short f2bf(float x) {   // RNE truncate to bf16
    unsigned u = __float_as_uint(x);
    unsigned r = ((u >> 16) & 1u) + 0x7fffu;
    return (unsigned short)((u + r) >> 16);
}
__device__ __forceinline__ float bf2f(unsigned short h) {
    return __uint_as_float(((unsigned)h) << 16);
}

// Builds W1T fp32 + bf16 hi/lo weight planes; zero-inits logdet region.
__global__ void setup_kernel(const float* __restrict__ W0, const float* __restrict__ W1,
                             const float* __restrict__ W2,
                             float* __restrict__ ws, float* __restrict__ out) {
    int d = blockIdx.x;
    float* w1t = ws + d * H_ * H_;
    unsigned short* bfw = (unsigned short*)(ws + WS_BF_OFF);
    for (int idx = threadIdx.x; idx < H_ * H_; idx += blockDim.x) {
        int r = idx >> 6, c = idx & 63;
        w1t[r * H_ + c] = W1[(d * H_ + c) * H_ + r];   // W1T[h_in][h_out]
        float w2v = W2[d * H_ * H_ + idx];
        unsigned short h2 = f2bf(w2v);
        bfw[UO_W2H + d * H_ * H_ + idx] = h2;
        bfw[UO_W2L + d * H_ * H_ + idx] = f2bf(w2v - bf2f(h2));
        float w1v = W1[d * H_ * H_ + idx];
        unsigned short h1 = f2bf(w1v);
        bfw[UO_W1H + d * H_ * H_ + idx] = h1;
        bfw[UO_W1L + d * H_ * H_ + idx] = f2bf(w1v - bf2f(h1));
    }
    for (int idx = threadIdx.x; idx < H_ * 32; idx += blockDim.x) {
        int j = idx >> 5, i = idx & 31;
        float v = (i < IN_) ? W0[(d * H_ + j) * IN_ + i] : 0.0f;
        unsigned short h = f2bf(v);
        bfw[UO_W0H + d * H_ * 32 + idx] = h;
        bfw[UO_W0L + d * H_ * 32 + idx] = f2bf(v - bf2f(h));
    }
    if (d == 0 && threadIdx.x < B_) out[LOG_OFF + threadIdx.x] = 0.0f;
}

// Forward only (fp32 VALU, proven R3 structure): residuals + mask stash.
// Masks are stashed in the hist_jac rows of d_out (overwritten later by bwd).
__global__ void fwd_kernel(
    const float* __restrict__ x,
    const float* __restrict__ W0, const float* __restrict__ b0,
    const float* __restrict__ b1, const float* __restrict__ W2,
    const float* __restrict__ b2, const float* __restrict__ Wo,
    const float* __restrict__ bo, const float* __restrict__ W1T,
    float* __restrict__ out)
{
    const int bid = blockIdx.x;
    const int d   = bid >> 8;
    const int rem = bid & 255;
    const int b   = rem >> 1;
    const int w   = ((rem & 1) << 8) | threadIdx.x;
    const int n   = b * W_ + w;

    const float* __restrict__ W0d  = W0  + d * (H_ * IN_);
    const float* __restrict__ b0d  = b0  + d * H_;
    const float* __restrict__ b1d  = b1  + d * H_;
    const float* __restrict__ W2d  = W2  + d * (H_ * H_);
    const float* __restrict__ b2d  = b2  + d * H_;
    const float* __restrict__ Wod  = Wo  + d * H_;
    const float* __restrict__ W1Td = W1T + d * (H_ * H_);

    float inp[IN_];
    {
        const float* xp = x + (b * T_ + w) * D_;
        const float4* xp4 = (const float4*)xp;
        float4 q0 = xp4[0], q1 = xp4[1], q2 = xp4[2], q3 = xp4[3];
        inp[0]=q0.x;  inp[1]=q0.y;  inp[2]=q0.z;  inp[3]=q0.w;
        inp[4]=q1.x;  inp[5]=q1.y;  inp[6]=q1.z;  inp[7]=q1.w;
        inp[8]=q2.x;  inp[9]=q2.y;  inp[10]=q2.z; inp[11]=q2.w;
        inp[12]=q3.x; inp[13]=q3.y; inp[14]=q3.z; inp[15]=q3.w;
        inp[16] = xp[16 + d];
    }

    float h1acc[H_];
#pragma unroll
    for (int g = 0; g < H_; ++g) h1acc[g] = b1d[g];

    unsigned long long m0 = 0ull;

#pragma unroll 1
    for (int h = 0; h < H_; ++h) {
        const float* w0r = W0d + h * IN_;
        float t0 = b0d[h], t1 = 0.f, t2 = 0.f, t3 = 0.f;
#pragma unroll
        for (int i = 0; i < 16; i += 4) {
            t0 = fmaf(inp[i+0], w0r[i+0], t0);
            t1 = fmaf(inp[i+1], w0r[i+1], t1);
            t2 = fmaf(inp[i+2], w0r[i+2], t2);
            t3 = fmaf(inp[i+3], w0r[i+3], t3);
        }
        t0 = fmaf(inp[16], w0r[16], t0);
        float hv = (t0 + t2) + (t1 + t3);
        bool  p  = hv > 0.0f;
        float a0h = p ? hv : hv * SLOPE_;
        m0 |= ((unsigned long long)p) << h;
        const float* w1tr = W1Td + h * H_;
#pragma unroll
        for (int g = 0; g < H_; ++g) h1acc[g] = fmaf(a0h, w1tr[g], h1acc[g]);
    }

    unsigned long long m1 = 0ull;
#pragma unroll
    for (int g = 0; g < H_; ++g) {
        float hv = h1acc[g];
        bool  p  = hv > 0.0f;
        m1 |= ((unsigned long long)p) << g;
        h1acc[g] = p ? hv : hv * SLOPE_;
    }

    unsigned long long m2 = 0ull;
    float outv = bo[d];
#pragma unroll 1
    for (int g = 0; g < H_; ++g) {
        const float* w2r = W2d + g * H_;
        float t0 = b2d[g], t1 = 0.f, t2 = 0.f, t3 = 0.f;
#pragma unroll
        for (int k = 0; k < H_; k += 4) {
            t0 = fmaf(h1acc[k+0], w2r[k+0], t0);
            t1 = fmaf(h1acc[k+1], w2r[k+1], t1);
            t2 = fmaf(h1acc[k+2], w2r[k+2], t2);
            t3 = fmaf(h1acc[k+3], w2r[k+3], t3);
        }
        float hv = (t0 + t2) + (t1 + t3);
        bool  p  = hv > 0.0f;
        m2 |= ((unsigned long long)p) << g;
        outv = fmaf(Wod[g], p ? hv : hv * SLOPE_, outv);
    }

    out[n * D_ + d] = outv;

    unsigned* outU = (unsigned*)out;
    size_t mi = (size_t)HJ_OFF + ((size_t)d * N_ + n) * 16;
    outU[mi+0] = (unsigned)(m0 & 0xffffffffull); outU[mi+1] = (unsigned)(m0 >> 32);
    outU[mi+2] = (unsigned)(m1 & 0xffffffffull); outU[mi+3] = (unsigned)(m1 >> 32);
    outU[mi+4] = (unsigned)(m2 & 0xffffffffull); outU[mi+5] = (unsigned)(m2 >> 32);
}

// Backward via MFMA split-bf16 (3-term): jac = (((Wo.m2)W2).m1 W1).m0 W0.
// One block = (d, 256-sample tile); 4 waves own disjoint 16-row M-tiles ->
// no barriers in the GEMM chain; activations round-trip through LDS.
#define ACT_S 68
__global__ __launch_bounds__(256, 2) void bwd_kernel(
    const float* __restrict__ Wo,
    const unsigned short* __restrict__ bfw,
    float* __restrict__ out)
{
    __shared__ float act[256 * ACT_S];
    __shared__ unsigned sm0[256 * 2];
    __shared__ unsigned sm1[256 * 2];
    __shared__ float red[4];

    const int blk = blockIdx.x;
    const int d   = blk >> 8;           // 256 tiles per d
    const int t   = blk & 255;
    const int n0  = t << 8;             // 256 samples
    const int bb  = n0 >> 9;            // batch row (tile fits in one b)

    const int tid  = threadIdx.x;
    const int wv   = tid >> 6;
    const int lane = tid & 63;
    const int q    = lane >> 4;
    const int c    = lane & 15;

    // ---- stage masks to LDS + build A1 = Wo * sel(m2) into act
    {
        const unsigned* outU = (const unsigned*)out;
        size_t mi = (size_t)HJ_OFF + ((size_t)d * N_ + (n0 + tid)) * 16;
        unsigned a0 = outU[mi+0], a1 = outU[mi+1];
        unsigned a2 = outU[mi+2], a3 = outU[mi+3];
        unsigned a4 = outU[mi+4], a5 = outU[mi+5];
        sm0[tid*2] = a0; sm0[tid*2+1] = a1;
        sm1[tid*2] = a2; sm1[tid*2+1] = a3;
        const float* Wod = Wo + d * H_;
        float* arow = act + tid * ACT_S;
#pragma unroll
        for (int g = 0; g < 64; g += 4) {
            unsigned mm = (g < 32) ? a4 : a5;
            float4 v;
            v.x = Wod[g+0] * (((mm >> ((g+0)&31)) & 1u) ? 1.0f : SLOPE_);
            v.y = Wod[g+1] * (((mm >> ((g+1)&31)) & 1u) ? 1.0f : SLOPE_);
            v.z = Wod[g+2] * (((mm >> ((g+2)&31)) & 1u) ? 1.0f : SLOPE_);
            v.w = Wod[g+3] * (((mm >> ((g+3)&31)) & 1u) ? 1.0f : SLOPE_);
            *(float4*)(arow + g) = v;
        }
    }
    __syncthreads();

    // ---- load B fragments (resident in regs; one-time per block)
    // B layout per lane: elem j = B[kst*32 + q*8 + j][nt*16 + c]
    const unsigned short* W2H = bfw + UO_W2H + d * H_ * H_;
    const unsigned short* W2L = bfw + UO_W2L + d * H_ * H_;
    const unsigned short* W1H = bfw + UO_W1H + d * H_ * H_;
    const unsigned short* W1L = bfw + UO_W1L + d * H_ * H_;
    const unsigned short* W0H = bfw + UO_W0H + d * H_ * 32;
    const unsigned short* W0L = bfw + UO_W0L + d * H_ * 32;

    short8 b1h[4][2], b1l[4][2], b2h[4][2], b2l[4][2], b3h[2][2], b3l[2][2];
#pragma unroll
    for (int nt = 0; nt < 4; ++nt)
#pragma unroll
        for (int kst = 0; kst < 2; ++kst)
#pragma unroll
            for (int j = 0; j < 8; ++j) {
                int k = kst*32 + q*8 + j, nn = nt*16 + c;
                b1h[nt][kst][j] = (short)W2H[k*64 + nn];
                b1l[nt][kst][j] = (short)W2L[k*64 + nn];
                b2h[nt][kst][j] = (short)W1H[k*64 + nn];
                b2l[nt][kst][j] = (short)W1L[k*64 + nn];
            }
#pragma unroll
    for (int nt = 0; nt < 2; ++nt)
#pragma unroll
        for (int kst = 0; kst < 2; ++kst)
#pragma unroll
            for (int j = 0; j < 8; ++j) {
                int k = kst*32 + q*8 + j, nn = nt*16 + c;
                b3h[nt][kst][j] = (short)W0H[k*32 + nn];
                b3l[nt][kst][j] = (short)W0L[k*32 + nn];
            }

    float ld = 0.0f;

#pragma unroll 1
    for (int mti = 0; mti < 4; ++mti) {
        const int row0 = (wv + mti*4) * 16;
        short8 ah[2], al[2];

        // A-frags from act (A[m=lane&15][k=q*8+j+32*kst])
#pragma unroll
        for (int kst = 0; kst < 2; ++kst) {
            const float* p = act + (row0 + c) * ACT_S + kst*32 + q*8;
            float4 f0 = *(const float4*)p;
            float4 f1 = *(const float4*)(p + 4);
            float xs[8] = {f0.x,f0.y,f0.z,f0.w,f1.x,f1.y,f1.z,f1.w};
#pragma unroll
            for (int j = 0; j < 8; ++j) {
                unsigned short hs = f2bf(xs[j]);
                ah[kst][j] = (short)hs;
                al[kst][j] = (short)f2bf(xs[j] - bf2f(hs));
            }
        }

        // GEMM1: x W2
        float4v acc[4];
#pragma unroll
        for (int nt = 0; nt < 4; ++nt) {
            float4v a = {0.f,0.f,0.f,0.f};
#pragma unroll
            for (int kst = 0; kst < 2; ++kst) {
                a = __builtin_amdgcn_mfma_f32_16x16x32_bf16(ah[kst], b1h[nt][kst], a, 0,0,0);
                a = __builtin_amdgcn_mfma_f32_16x16x32_bf16(al[kst], b1h[nt][kst], a, 0,0,0);
                a = __builtin_amdgcn_mfma_f32_16x16x32_bf16(ah[kst], b1l[nt][kst], a, 0,0,0);
            }
            acc[nt] = a;
        }
        // mask m1, write back to act
#pragma unroll
        for (int nt = 0; nt < 4; ++nt)
#pragma unroll
            for (int r = 0; r < 4; ++r) {
                int row = row0 + q*4 + r, col = nt*16 + c;
                unsigned bit = (sm1[row*2 + (col>>5)] >> (col&31)) & 1u;
                act[row*ACT_S + col] = acc[nt][r] * (bit ? 1.0f : SLOPE_);
            }

        // A2-frags
#pragma unroll
        for (int kst = 0; kst < 2; ++kst) {
            const float* p = act + (row0 + c) * ACT_S + kst*32 + q*8;
            float4 f0 = *(const float4*)p;
            float4 f1 = *(const float4*)(p + 4);
            float xs[8] = {f0.x,f0.y,f0.z,f0.w,f1.x,f1.y,f1.z,f1.w};
#pragma unroll
            for (int j = 0; j < 8; ++j) {
                unsigned short hs = f2bf(xs[j]);
                ah[kst][j] = (short)hs;
                al[kst][j] = (short)f2bf(xs[j] - bf2f(hs));
            }
        }

        // GEMM2: x W1
#pragma unroll
        for (int nt = 0; nt < 4; ++nt) {
            float4v a = {0.f,0.f,0.f,0.f};
#pragma unroll
            for (int kst = 0; kst < 2; ++kst) {
                a = __builtin_amdgcn_mfma_f32_16x16x32_bf16(ah[kst], b2h[nt][kst], a, 0,0,0);
                a = __builtin_amdgcn_mfma_f32_16x16x32_bf16(al[kst], b2h[nt][kst], a, 0,0,0);
                a = __builtin_amdgcn_mfma_f32_16x16x32_bf16(ah[kst], b2l[nt][kst], a, 0,0,0);
            }
            acc[nt] = a;
        }
        // mask m0, write back
#pragma unroll
        for (int nt = 0; nt < 4; ++nt)
#pragma unroll
            for (int r = 0; r < 4; ++r) {
                int row = row0 + q*4 + r, col = nt*16 + c;
                unsigned bit = (sm0[row*2 + (col>>5)] >> (col&31)) & 1u;
                act[row*ACT_S + col] = acc[nt][r] * (bit ? 1.0f : SLOPE_);
            }

        // A3-frags
#pragma unroll
        for (int kst = 0; kst < 2; ++kst) {
            const float* p = act + (row0 + c) * ACT_S + kst*32 + q*8;
            float4 f0 = *(const float4*)p;
            float4 f1 = *(const float4*)(p + 4);
            float xs[8] = {f0.x,f0.y,f0.z,f0.w,f1.x,f1.y,f1.z,f1.w};
#pragma unroll
            for (int j = 0; j < 8; ++j) {
                unsigned short hs = f2bf(xs[j]);
                ah[kst][j] = (short)hs;
                al[kst][j] = (short)f2bf(xs[j] - bf2f(hs));
            }
        }

        // GEMM3: x W0 (N=32 padded; col16 = jac[...,16])
#pragma unroll
        for (int nt = 0; nt < 2; ++nt) {
            float4v a = {0.f,0.f,0.f,0.f};
#pragma unroll
            for (int kst = 0; kst < 2; ++kst) {
                a = __builtin_amdgcn_mfma_f32_16x16x32_bf16(ah[kst], b3h[nt][kst], a, 0,0,0);
                a = __builtin_amdgcn_mfma_f32_16x16x32_bf16(al[kst], b3h[nt][kst], a, 0,0,0);
                a = __builtin_amdgcn_mfma_f32_16x16x32_bf16(ah[kst], b3l[nt][kst], a, 0,0,0);
            }
            acc[nt] = a;
        }

        // epilogue: hist_jac cols 0..15 from nt0; logdet from nt1 col16 (c==0)
#pragma unroll
        for (int r = 0; r < 4; ++r) {
            int row = row0 + q*4 + r;
            out[HJ_OFF + ((size_t)d * N_ + (n0 + row)) * 16 + c] = acc[0][r];
        }
        if (c == 0) {
#pragma unroll
            for (int r = 0; r < 4; ++r) ld += logf(fabsf(acc[1][r]));
        }
    }

    // reduce logdet
#pragma unroll
    for (int off = 32; off > 0; off >>= 1)
        ld += __shfl_down(ld, off, 64);
    if (lane == 0) red[wv] = ld;
    __syncthreads();
    if (tid == 0)
        atomicAdd(out + LOG_OFF + bb, (red[0] + red[1]) + (red[2] + red[3]));
}

extern "C" void kernel_launch(void* const* d_in, const int* in_sizes, int n_in,
                              void* d_out, int out_size, void* d_ws, size_t ws_size,
                              hipStream_t stream) {
    const float* x  = (const float*)d_in[0];
    const float* W0 = (const float*)d_in[1];
    const float* b0 = (const float*)d_in[2];
    const float* W1 = (const float*)d_in[3];
    const float* b1 = (const float*)d_in[4];
    const float* W2 = (const float*)d_in[5];
    const float* b2 = (const float*)d_in[6];
    const float* Wo = (const float*)d_in[7];
    const float* bo = (const float*)d_in[8];
    float* out = (float*)d_out;
    float* ws  = (float*)d_ws;   // W1T 128KB + bf16 planes ~320KB
    const unsigned short* bfw = (const unsigned short*)(ws + WS_BF_OFF);

    hipLaunchKernelGGL(setup_kernel, dim3(D_), dim3(256), 0, stream, W0, W1, W2, ws, out);
    hipLaunchKernelGGL(fwd_kernel, dim3(D_ * B_ * 2), dim3(256), 0, stream,
                       x, W0, b0, b1, W2, b2, Wo, bo, ws, out);
    hipLaunchKernelGGL(bwd_kernel, dim3(D_ * 256), dim3(256), 0, stream,
                       Wo, bfw, out);
}